// Round 7
// baseline (243.970 us; speedup 1.0000x reference)
//
#include <hip/hip_runtime.h>
#include <math.h>

// ToneStack: 3 cascaded shelf biquads over x[64, 480000] fp32.
//
// R11 = R10 + wave-coalesced LOAD staging (mirror of the R5 store fix).
//   R10 answered the barrier question: 22 -> 2 barriers bought only ~2us
//   (85us, VALUBusy 43%, occ 31%). Remaining stall: the 16 per-thread
//   global_load_dwordx4 at 256B inter-lane stride -> each wave-load
//   instruction gathers 64 distinct 128B lines (8x line-transaction
//   amplification, L1 thrash at 16KB/wave x ~10 waves). Fix, per wave,
//   barrier-free, before everything else: 4 rounds; round j = all 64
//   lanes load 4x 1KB-CONTIGUOUS float4 (8 full lines per instr, fully
//   consumed) -> ds_write swizzled into the wave's 4KB quarter -> the
//   round's 16 owner lanes ds_read their 16 float4 into xv. Same swizzle
//   involution + same intra-wave in-order DS guarantee as the store path.
//   Line transactions per wave: 1024 -> 128. dl moved OUT of the quarter
//   region (smem+16KB) so staging never aliases dl across waves (LDS
//   19.9 -> 26.6KB, still 4 blocks/CU by LDS).
//   Everything else identical to R10: (256,4) bound (reg floor >102 --
//   R7/R9 spilled at 64/85 caps), 2 barriers, wave-0 shuffle A-powers,
//   wave-1 cn table, HISTC=MTERM=17, superposition combine, per-wave
//   store staging. Output bitwise identical to R10 (absmax 0.03125).

constexpr int T_LEN  = 480000;
constexpr int B_ROWS = 64;
constexpr int CHUNK  = 64;
constexpr int LOG2C  = 6;                     // A^64 = 6 squarings
constexpr int KCH    = T_LEN / CHUNK;         // 7500 chunks per row
constexpr int NT     = 256;                   // threads per block
constexpr int HISTC  = 17;                    // history chunks (1088 samples)
constexpr int MTERM  = 17;                    // Horner terms (= horizon)
constexpr int OUTC   = NT - HISTC;            // 239 output chunks per block
constexpr int BLKROW = (KCH + OUTC - 1) / OUTC;  // 32 blocks per row
constexpr int NBLK   = B_ROWS * BLKROW;       // 2048 blocks

struct Coeffs { float b0, b1, b2, a1, a2; };

__device__ __forceinline__ float rfl(float v) {
    return __int_as_float(__builtin_amdgcn_readfirstlane(__float_as_int(v)));
}

__device__ __forceinline__ Coeffs shelf(float fc, float gdb, float Q) {
    float A  = powf(10.0f, gdb * (1.0f / 40.0f));
    float w0 = 2.0f * 3.14159265358979323846f * fc / 48000.0f;
    float sw = sinf(w0), cw = cosf(w0);
    float alpha = sw / (2.0f * Q);
    float sqA = sqrtf(A);
    float b0 = A * ((A + 1.0f) - (A - 1.0f) * cw + 2.0f * sqA * alpha);
    float b1 = 2.0f * A * ((A - 1.0f) - (A + 1.0f) * cw);
    float b2 = A * ((A + 1.0f) - (A - 1.0f) * cw - 2.0f * sqA * alpha);
    float a0 = (A + 1.0f) + (A - 1.0f) * cw + 2.0f * sqA * alpha;
    float a1 = -2.0f * ((A - 1.0f) + (A + 1.0f) * cw);
    float a2 = (A + 1.0f) + (A - 1.0f) * cw - 2.0f * sqA * alpha;
    float rr = 1.0f / a0;
    Coeffs c;
    c.b0 = rfl(b0 * rr); c.b1 = rfl(b1 * rr); c.b2 = rfl(b2 * rr);
    c.a1 = rfl(a1 * rr); c.a2 = rfl(a2 * rr);
    return c;
}

// DF2T biquad step, op-for-op as reference:
//   y = b0*x + z1; z1' = b1*x - a1*y + z2; z2' = b2*x - a2*y
__device__ __forceinline__ float bq(float xn, const Coeffs& c, float& z1, float& z2) {
    float y = fmaf(c.b0, xn, z1);
    z1 = fmaf(-c.a1, y, fmaf(c.b1, xn, z2));
    z2 = fmaf(c.b2, xn, -(c.a2 * y));
    return y;
}

__device__ __forceinline__ float step6(float s[6], float x,
                                       const Coeffs& c1, const Coeffs& c2, const Coeffs& c3) {
    float y1 = bq(x,  c1, s[0], s[1]);
    float y2 = bq(y1, c2, s[2], s[3]);
    float y3 = bq(y2, c3, s[4], s[5]);
    return y3;
}

// y0 + cn[n].t6 (cn rows stride-8; broadcast LDS reads, const offsets)
__device__ __forceinline__ float corr(float y0, const float* cnp, const float t6[6]) {
    float4 ca = *(const float4*)(cnp);
    float2 cb = *(const float2*)(cnp + 4);
    float acc = fmaf(ca.x, t6[0], y0);
    acc = fmaf(ca.y, t6[1], acc);
    acc = fmaf(ca.z, t6[2], acc);
    acc = fmaf(ca.w, t6[3], acc);
    acc = fmaf(cb.x, t6[4], acc);
    acc = fmaf(cb.y, t6[5], acc);
    return acc;
}

__global__ __launch_bounds__(256, 4) void k_fused(
    const float* __restrict__ x,
    const float* __restrict__ p_lg, const float* __restrict__ p_mg,
    const float* __restrict__ p_mf, const float* __restrict__ p_mq,
    const float* __restrict__ p_hg,
    float* __restrict__ out)
{
    // [0 .. 4096): four per-wave 4KB quarters (load staging, then store
    //              staging -- load data dead by barrier2).
    // [4096 .. 5888): per-thread d store (dl, stride 7) -- disjoint from
    //              the quarters so per-wave staging never aliases dl.
    __shared__ __align__(16) float smem[4096 + NT * 7];
    __shared__ float M[36];                      // A^64
    __shared__ float Pw[LOG2C * 36];             // A^1,A^2,A^4,A^8,A^16,A^32
    __shared__ float Crow[8];                    // output row C of the cascade
    __shared__ __align__(16) float cn[64 * 8];   // C*A^n rows, stride 8

    const int t    = threadIdx.x;
    const int lane = t & 63;
    const int w    = t >> 6;
    const int r = blockIdx.x / BLKROW;
    const int b = blockIdx.x - r * BLKROW;
    const int c = b * OUTC + t - HISTC;          // this thread's chunk index
    const int cbase = b * OUTC - HISTC;          // chunk index of thread 0
    const bool active = (c >= 0) && (c < KCH);

    Coeffs c1 = shelf(120.0f,  *p_lg, 0.707f);
    Coeffs c2 = shelf(*p_mf,   *p_mg, *p_mq);
    Coeffs c3 = shelf(4000.0f, *p_hg, 0.707f);

    // ---- wave-coalesced load staging (per-wave, barrier-free) ----
    // Round j fills the chunks of lanes 16j..16j+15: all 64 lanes load
    // 4x 1KB-contiguous float4 and ds_write into this wave's quarter
    // (swizzled); the 16 owner lanes then ds_read their chunk into xv.
    float4* qv = ((float4*)smem) + w * 256;       // this wave's 4KB quarter
    float4 xv[16];
    {
        const float4* ip = (const float4*)x;
        const long long totF4 = (long long)B_ROWS * (T_LEN / 4);
        const long long rowF4 = (long long)r * (T_LEN / 4);
        for (int j = 0; j < 4; ++j) {
            const long long base4 = rowF4 + (long long)(cbase + w * 64 + 16 * j) * 16;
            float4 tmp[4];
            #pragma unroll
            for (int i = 0; i < 4; ++i) {
                long long g = base4 + i * 64 + lane;
                g = g < 0 ? 0 : (g >= totF4 ? totF4 - 1 : g);  // clamp (owners of OOB chunks are inactive)
                tmp[i] = ip[g];
            }
            #pragma unroll
            for (int i = 0; i < 4; ++i) {
                const int sl = i * 4 + (lane >> 4);   // slot in quarter
                const int qq = lane & 15;             // float4 within chunk
                qv[sl * 16 + (qq ^ (sl & 7))] = tmp[i];
            }
            if ((lane >> 4) == j) {                   // own-round readback
                const int sl  = lane & 15;
                const int key = sl & 7;
                #pragma unroll
                for (int q = 0; q < 16; ++q)
                    xv[q] = qv[sl * 16 + (q ^ key)];
            }
        }
        if (!active) {
            #pragma unroll
            for (int q = 0; q < 16; ++q) xv[q] = make_float4(0.f, 0.f, 0.f, 0.f);
        }
    }

    // ---- wave 0: A columns + C row, then 6 shuffle-squarings, publish ----
    // Lane (i,j) = lane i*6+j holds A[i][j]; identical fma order to the
    // LDS version (acc=0; acc=fma(A[i][q],A[q][j],acc), q ascending).
    if (w == 0) {
        const int i  = lane / 6;                 // lanes >=36: clamped, unused
        const int j  = lane - 6 * i;
        const int i6 = i * 6;
        float e[6];
        #pragma unroll
        for (int jj = 0; jj < 6; ++jj) e[jj] = (jj == j) ? 1.0f : 0.0f;
        float y = step6(e, 0.0f, c1, c2, c3);    // e := A[:,j]; y = C[j]
        if (lane < 6) Crow[lane] = y;
        float aM = e[0];
        #pragma unroll
        for (int ii = 1; ii < 6; ++ii) aM = (i == ii) ? e[ii] : aM;
        for (int it = 0; it < LOG2C; ++it) {
            if (lane < 36) Pw[it * 36 + lane] = aM;   // snapshot A^(2^it)
            float acc = 0.f;
            #pragma unroll
            for (int q = 0; q < 6; ++q) {
                int sA = i6 + q; if (sA > 63) sA = 63;   // lanes >=36 only
                acc = fmaf(__shfl(aM, sA, 64), __shfl(aM, q * 6 + j, 64), acc);
            }
            aM = acc;
        }
        if (lane < 36) M[lane] = aM;             // A^64
    }

    // ---- pass 1: zero-state response, outputs written in place (y0) ----
    float s[6] = {0.f, 0.f, 0.f, 0.f, 0.f, 0.f};
    #pragma unroll
    for (int q = 0; q < 16; ++q) {
        float4 v = xv[q];
        v.x = step6(s, v.x, c1, c2, c3);
        v.y = step6(s, v.y, c1, c2, c3);
        v.z = step6(s, v.z, c1, c2, c3);
        v.w = step6(s, v.w, c1, c2, c3);
        xv[q] = v;
    }
    float* dl = smem + 4096;
    #pragma unroll
    for (int i = 0; i < 6; ++i) dl[t * 7 + i] = s[i];

    __syncthreads();                              // barrier1: dl + M + Pw + Crow

    float a[36];
    #pragma unroll
    for (int i = 0; i < 36; ++i) a[i] = rfl(M[i]);   // A^64 -> SGPRs

    // ---- cn rows on wave 1: cn[n] = C * prod_k A^(2^k * bit_k(n)) ----
    if (w == 1) {
        float row[6];
        #pragma unroll
        for (int jj = 0; jj < 6; ++jj) row[jj] = Crow[jj];
        #pragma unroll
        for (int k = 0; k < LOG2C; ++k) {
            if ((lane >> k) & 1) {
                const float* P = Pw + k * 36;
                float nr[6];
                #pragma unroll
                for (int jj = 0; jj < 6; ++jj) {
                    float acc = 0.f;
                    #pragma unroll
                    for (int q = 0; q < 6; ++q) acc = fmaf(row[q], P[q * 6 + jj], acc);
                    nr[jj] = acc;
                }
                #pragma unroll
                for (int jj = 0; jj < 6; ++jj) row[jj] = nr[jj];
            }
        }
        #pragma unroll
        for (int jj = 0; jj < 6; ++jj) cn[lane * 8 + jj] = row[jj];
    }

    // ---- truncated Horner scan over predecessors (oldest -> newest) ----
    float t6[6] = {0.f, 0.f, 0.f, 0.f, 0.f, 0.f};
    int m0 = t - MTERM; if (m0 < 0) m0 = 0;
    for (int m = m0; m < t; ++m) {
        float dm[6];
        #pragma unroll
        for (int i = 0; i < 6; ++i) dm[i] = dl[m * 7 + i];
        float nt6[6];
        #pragma unroll
        for (int i = 0; i < 6; ++i) {
            float acc = dm[i];
            #pragma unroll
            for (int j = 0; j < 6; ++j) acc = fmaf(a[i * 6 + j], t6[j], acc);
            nt6[i] = acc;
        }
        #pragma unroll
        for (int i = 0; i < 6; ++i) t6[i] = nt6[i];
    }

    __syncthreads();   // barrier2: cn ready; load data in quarters dead

    // ---- combine: y[n] = y0[n] + cn[n].t6  (6 fma + 2 LDS bcast/sample) ----
    #pragma unroll
    for (int q = 0; q < 16; ++q) {
        float4 v = xv[q];
        v.x = corr(v.x, cn + (4 * q + 0) * 8, t6);
        v.y = corr(v.y, cn + (4 * q + 1) * 8, t6);
        v.z = corr(v.z, cn + (4 * q + 2) * 8, t6);
        v.w = corr(v.w, cn + (4 * q + 3) * 8, t6);
        xv[q] = v;
    }

    // ---- per-wave store staging, barrier-free (R5/R10 proven path) ----
    // Round j: source lanes 16j..16j+15 write their chunks (swizzled)
    // into this wave's quarter; all 64 lanes read back + store
    // 1KB-contiguous global. DS ops retire in-order per wave.
    float4* op = (float4*)(out + (long long)r * T_LEN);
    #pragma unroll
    for (int j = 0; j < 4; ++j) {
        if ((lane >> 4) == j) {
            const int sl  = lane & 15;
            const int key = sl & 7;
            #pragma unroll
            for (int q = 0; q < 16; ++q)
                qv[sl * 16 + (q ^ key)] = xv[q];
        }
        const long long base4 = (long long)(cbase + w * 64 + 16 * j) * 16;
        #pragma unroll
        for (int i = 0; i < 4; ++i) {
            const int sl = i * 4 + (lane >> 4);   // source slot in quarter
            const int qq = lane & 15;             // float4 within chunk
            const int tr = w * 64 + 16 * j + sl;  // owning thread index
            const int cc = cbase + tr;            // destination chunk
            if (tr >= HISTC && cc < KCH) {
                op[base4 + i * 64 + lane] = qv[sl * 16 + (qq ^ (sl & 7))];
            }
        }
    }
}

extern "C" void kernel_launch(void* const* d_in, const int* in_sizes, int n_in,
                              void* d_out, int out_size, void* d_ws, size_t ws_size,
                              hipStream_t stream) {
    const float* x  = (const float*)d_in[0];
    const float* lg = (const float*)d_in[1];
    const float* mg = (const float*)d_in[2];
    const float* mf = (const float*)d_in[3];
    const float* mq = (const float*)d_in[4];
    const float* hg = (const float*)d_in[5];
    float* out = (float*)d_out;

    hipLaunchKernelGGL(k_fused, dim3(NBLK), dim3(NT), 0, stream,
                       x, lg, mg, mf, mq, hg, out);
}

// Round 8
// 232.846 us; speedup vs baseline: 1.0478x; 1.0478x over previous
//
#include <hip/hip_runtime.h>
#include <math.h>

// ToneStack: 3 cascaded shelf biquads over x[64, 480000] fp32.
//
// R12 = R10 with MTERM/HISTC 17 -> 12.
//   R11 post-mortem: wave-coalesced load staging compiled as a depth-1
//   serial pipeline AND cost LDS (27KB -> 5 blocks/CU = 20 waves vs
//   R10's 32); wall scales ~1/resident-waves for this stall-bound kernel
//   (R6: 8 waves = 104us, R11: 20 = 127us, R10: 32 = 85us). Load-path
//   restructuring is rejected: any scheme costing LDS (>20KB) or VGPR
//   (>64) loses more parallelism than it saves L1 transactions.
//   Protected invariant: VGPR<=64, LDS<20KB, 8 blocks/CU, (256,4).
//   This round cuts issue work instead: the Horner scan is 714 of ~2300
//   core VALU/thread. Slowest pole (120Hz shelf, Q=0.707) r~0.9889/sample
//   -> 0.49/chunk; truncated mass at 12 chunks ~1e-3 << 0.03125 floor
//   (floor proven horizon-independent across MTERM 24/21/17).
//   MTERM/HISTC=12: Horner -29%, history overhead 7.1->4.9%,
//   OUTC=244, BLKROW=31, NBLK=1984. Everything else bit-identical to
//   R10 (2 barriers, wave-0 shuffle A-powers, wave-1 cn table,
//   superposition combine, per-wave barrier-free store staging).

constexpr int T_LEN  = 480000;
constexpr int B_ROWS = 64;
constexpr int CHUNK  = 64;
constexpr int LOG2C  = 6;                     // A^64 = 6 squarings
constexpr int KCH    = T_LEN / CHUNK;         // 7500 chunks per row
constexpr int NT     = 256;                   // threads per block
constexpr int HISTC  = 12;                    // history chunks (768 samples)
constexpr int MTERM  = 12;                    // Horner terms (= horizon)
constexpr int OUTC   = NT - HISTC;            // 244 output chunks per block
constexpr int BLKROW = (KCH + OUTC - 1) / OUTC;  // 31 blocks per row
constexpr int NBLK   = B_ROWS * BLKROW;       // 1984 blocks

struct Coeffs { float b0, b1, b2, a1, a2; };

__device__ __forceinline__ float rfl(float v) {
    return __int_as_float(__builtin_amdgcn_readfirstlane(__float_as_int(v)));
}

__device__ __forceinline__ Coeffs shelf(float fc, float gdb, float Q) {
    float A  = powf(10.0f, gdb * (1.0f / 40.0f));
    float w0 = 2.0f * 3.14159265358979323846f * fc / 48000.0f;
    float sw = sinf(w0), cw = cosf(w0);
    float alpha = sw / (2.0f * Q);
    float sqA = sqrtf(A);
    float b0 = A * ((A + 1.0f) - (A - 1.0f) * cw + 2.0f * sqA * alpha);
    float b1 = 2.0f * A * ((A - 1.0f) - (A + 1.0f) * cw);
    float b2 = A * ((A + 1.0f) - (A - 1.0f) * cw - 2.0f * sqA * alpha);
    float a0 = (A + 1.0f) + (A - 1.0f) * cw + 2.0f * sqA * alpha;
    float a1 = -2.0f * ((A - 1.0f) + (A + 1.0f) * cw);
    float a2 = (A + 1.0f) + (A - 1.0f) * cw - 2.0f * sqA * alpha;
    float rr = 1.0f / a0;
    Coeffs c;
    c.b0 = rfl(b0 * rr); c.b1 = rfl(b1 * rr); c.b2 = rfl(b2 * rr);
    c.a1 = rfl(a1 * rr); c.a2 = rfl(a2 * rr);
    return c;
}

// DF2T biquad step, op-for-op as reference:
//   y = b0*x + z1; z1' = b1*x - a1*y + z2; z2' = b2*x - a2*y
__device__ __forceinline__ float bq(float xn, const Coeffs& c, float& z1, float& z2) {
    float y = fmaf(c.b0, xn, z1);
    z1 = fmaf(-c.a1, y, fmaf(c.b1, xn, z2));
    z2 = fmaf(c.b2, xn, -(c.a2 * y));
    return y;
}

__device__ __forceinline__ float step6(float s[6], float x,
                                       const Coeffs& c1, const Coeffs& c2, const Coeffs& c3) {
    float y1 = bq(x,  c1, s[0], s[1]);
    float y2 = bq(y1, c2, s[2], s[3]);
    float y3 = bq(y2, c3, s[4], s[5]);
    return y3;
}

// y0 + cn[n].t6 (cn rows stride-8; broadcast LDS reads, const offsets)
__device__ __forceinline__ float corr(float y0, const float* cnp, const float t6[6]) {
    float4 ca = *(const float4*)(cnp);
    float2 cb = *(const float2*)(cnp + 4);
    float acc = fmaf(ca.x, t6[0], y0);
    acc = fmaf(ca.y, t6[1], acc);
    acc = fmaf(ca.z, t6[2], acc);
    acc = fmaf(ca.w, t6[3], acc);
    acc = fmaf(cb.x, t6[4], acc);
    acc = fmaf(cb.y, t6[5], acc);
    return acc;
}

__global__ __launch_bounds__(256, 4) void k_fused(
    const float* __restrict__ x,
    const float* __restrict__ p_lg, const float* __restrict__ p_mg,
    const float* __restrict__ p_mf, const float* __restrict__ p_mq,
    const float* __restrict__ p_hg,
    float* __restrict__ out)
{
    // smem: [0..1792) doubles as the per-thread d store (dl, stride 7);
    // after barrier2 the 16KB is four per-wave 4KB store-staging quarters.
    __shared__ __align__(16) float smem[4096];
    __shared__ float M[36];                      // A^64
    __shared__ float Pw[LOG2C * 36];             // A^1,A^2,A^4,A^8,A^16,A^32
    __shared__ float Crow[8];                    // output row C of the cascade
    __shared__ __align__(16) float cn[64 * 8];   // C*A^n rows, stride 8

    const int t    = threadIdx.x;
    const int lane = t & 63;
    const int w    = t >> 6;
    const int r = blockIdx.x / BLKROW;
    const int b = blockIdx.x - r * BLKROW;
    const int c = b * OUTC + t - HISTC;          // this thread's chunk index
    const int cbase = b * OUTC - HISTC;          // chunk index of thread 0
    const bool active = (c >= 0) && (c < KCH);

    Coeffs c1 = shelf(120.0f,  *p_lg, 0.707f);
    Coeffs c2 = shelf(*p_mf,   *p_mg, *p_mq);
    Coeffs c3 = shelf(4000.0f, *p_hg, 0.707f);

    // ---- load chunk into registers (issued first; latency hidden under
    //      wave 0's matrix work / other waves' residency) ----
    float4 xv[16];
    {
        int cc = c < 0 ? 0 : c;
        const float4* lp = (const float4*)(x + (long long)r * T_LEN + (long long)cc * CHUNK);
        if (active) {
            #pragma unroll
            for (int q = 0; q < 16; ++q) xv[q] = lp[q];
        } else {
            #pragma unroll
            for (int q = 0; q < 16; ++q) xv[q] = make_float4(0.f, 0.f, 0.f, 0.f);
        }
    }

    // ---- wave 0: A columns + C row, then 6 shuffle-squarings, publish ----
    // Lane (i,j) = lane i*6+j holds A[i][j]; identical fma order to the
    // LDS version (acc=0; acc=fma(A[i][q],A[q][j],acc), q ascending).
    if (w == 0) {
        const int i  = lane / 6;                 // lanes >=36: clamped, unused
        const int j  = lane - 6 * i;
        const int i6 = i * 6;
        float e[6];
        #pragma unroll
        for (int jj = 0; jj < 6; ++jj) e[jj] = (jj == j) ? 1.0f : 0.0f;
        float y = step6(e, 0.0f, c1, c2, c3);    // e := A[:,j]; y = C[j]
        if (lane < 6) Crow[lane] = y;
        float aM = e[0];
        #pragma unroll
        for (int ii = 1; ii < 6; ++ii) aM = (i == ii) ? e[ii] : aM;
        for (int it = 0; it < LOG2C; ++it) {
            if (lane < 36) Pw[it * 36 + lane] = aM;   // snapshot A^(2^it)
            float acc = 0.f;
            #pragma unroll
            for (int q = 0; q < 6; ++q) {
                int sA = i6 + q; if (sA > 63) sA = 63;   // lanes >=36 only
                acc = fmaf(__shfl(aM, sA, 64), __shfl(aM, q * 6 + j, 64), acc);
            }
            aM = acc;
        }
        if (lane < 36) M[lane] = aM;             // A^64
    }

    // ---- pass 1: zero-state response, outputs written in place (y0) ----
    float s[6] = {0.f, 0.f, 0.f, 0.f, 0.f, 0.f};
    #pragma unroll
    for (int q = 0; q < 16; ++q) {
        float4 v = xv[q];
        v.x = step6(s, v.x, c1, c2, c3);
        v.y = step6(s, v.y, c1, c2, c3);
        v.z = step6(s, v.z, c1, c2, c3);
        v.w = step6(s, v.w, c1, c2, c3);
        xv[q] = v;
    }
    #pragma unroll
    for (int i = 0; i < 6; ++i) smem[t * 7 + i] = s[i];

    __syncthreads();                              // barrier1: dl + M + Pw + Crow

    float a[36];
    #pragma unroll
    for (int i = 0; i < 36; ++i) a[i] = rfl(M[i]);   // A^64 -> SGPRs

    // ---- cn rows on wave 1: cn[n] = C * prod_k A^(2^k * bit_k(n)) ----
    if (w == 1) {
        float row[6];
        #pragma unroll
        for (int jj = 0; jj < 6; ++jj) row[jj] = Crow[jj];
        #pragma unroll
        for (int k = 0; k < LOG2C; ++k) {
            if ((lane >> k) & 1) {
                const float* P = Pw + k * 36;
                float nr[6];
                #pragma unroll
                for (int jj = 0; jj < 6; ++jj) {
                    float acc = 0.f;
                    #pragma unroll
                    for (int q = 0; q < 6; ++q) acc = fmaf(row[q], P[q * 6 + jj], acc);
                    nr[jj] = acc;
                }
                #pragma unroll
                for (int jj = 0; jj < 6; ++jj) row[jj] = nr[jj];
            }
        }
        #pragma unroll
        for (int jj = 0; jj < 6; ++jj) cn[lane * 8 + jj] = row[jj];
    }

    // ---- truncated Horner scan over predecessors (oldest -> newest) ----
    float t6[6] = {0.f, 0.f, 0.f, 0.f, 0.f, 0.f};
    int m0 = t - MTERM; if (m0 < 0) m0 = 0;
    for (int m = m0; m < t; ++m) {
        float dm[6];
        #pragma unroll
        for (int i = 0; i < 6; ++i) dm[i] = smem[m * 7 + i];
        float nt6[6];
        #pragma unroll
        for (int i = 0; i < 6; ++i) {
            float acc = dm[i];
            #pragma unroll
            for (int j = 0; j < 6; ++j) acc = fmaf(a[i * 6 + j], t6[j], acc);
            nt6[i] = acc;
        }
        #pragma unroll
        for (int i = 0; i < 6; ++i) t6[i] = nt6[i];
    }

    __syncthreads();   // barrier2: cn ready; all dl reads done (smem reusable)

    // ---- combine: y[n] = y0[n] + cn[n].t6  (6 fma + 2 LDS bcast/sample) ----
    #pragma unroll
    for (int q = 0; q < 16; ++q) {
        float4 v = xv[q];
        v.x = corr(v.x, cn + (4 * q + 0) * 8, t6);
        v.y = corr(v.y, cn + (4 * q + 1) * 8, t6);
        v.z = corr(v.z, cn + (4 * q + 2) * 8, t6);
        v.w = corr(v.w, cn + (4 * q + 3) * 8, t6);
        xv[q] = v;
    }

    // ---- per-wave store staging, barrier-free (R5/R10 proven path) ----
    // Round j: source lanes 16j..16j+15 write their chunks (swizzled)
    // into this wave's quarter; all 64 lanes read back + store
    // 1KB-contiguous global. DS ops retire in-order per wave.
    float4* qv = ((float4*)smem) + w * 256;       // this wave's quarter
    float4* op = (float4*)(out + (long long)r * T_LEN);
    #pragma unroll
    for (int j = 0; j < 4; ++j) {
        if ((lane >> 4) == j) {
            const int sl  = lane & 15;
            const int key = sl & 7;
            #pragma unroll
            for (int q = 0; q < 16; ++q)
                qv[sl * 16 + (q ^ key)] = xv[q];
        }
        const long long base4 = (long long)(cbase + w * 64 + 16 * j) * 16;
        #pragma unroll
        for (int i = 0; i < 4; ++i) {
            const int sl = i * 4 + (lane >> 4);   // source slot in quarter
            const int qq = lane & 15;             // float4 within chunk
            const int tr = w * 64 + 16 * j + sl;  // owning thread index
            const int cc = cbase + tr;            // destination chunk
            if (tr >= HISTC && cc < KCH) {
                op[base4 + i * 64 + lane] = qv[sl * 16 + (qq ^ (sl & 7))];
            }
        }
    }
}

extern "C" void kernel_launch(void* const* d_in, const int* in_sizes, int n_in,
                              void* d_out, int out_size, void* d_ws, size_t ws_size,
                              hipStream_t stream) {
    const float* x  = (const float*)d_in[0];
    const float* lg = (const float*)d_in[1];
    const float* mg = (const float*)d_in[2];
    const float* mf = (const float*)d_in[3];
    const float* mq = (const float*)d_in[4];
    const float* hg = (const float*)d_in[5];
    float* out = (float*)d_out;

    hipLaunchKernelGGL(k_fused, dim3(NBLK), dim3(NT), 0, stream,
                       x, lg, mg, mf, mq, hg, out);
}

// Round 9
// 227.448 us; speedup vs baseline: 1.0726x; 1.0237x over previous
//
#include <hip/hip_runtime.h>
#include <math.h>

// ToneStack: 3 cascaded shelf biquads over x[64, 480000] fp32.
//
// R13 = R12 with NT 256 -> 128 (2 waves/block). Single-variable test of
//   the phase-convergence theory: R12 proved issue work is NOT critical
//   (Horner -29% -> wall +-0); barriers proved cheap (R10); memory
//   restructuring proved net-negative under the residency envelope
//   (R6/R11). Remaining hypothesis: 4-wave barrier gangs + converged
//   launch keep all resident waves in the SAME phase (load burst /
//   compute / store burst), so memory and compute phases never overlap
//   across the CU. NT=128 doubles independent progress streams per CU
//   (8 -> ~14 resident blocks, LDS ~11KB/block) and halves barrier
//   blast radius, at +4.9% work (history 12/128 vs 12/256).
//   Per-thread math identical; chunk values depend only on own input +
//   12 predecessors' d -> output bitwise identical (absmax 0.03125).
//   Envelope preserved: (128,4) keeps the 128-reg/wave budget of
//   (256,4); VGPR<=64, no spill expected.

constexpr int T_LEN  = 480000;
constexpr int B_ROWS = 64;
constexpr int CHUNK  = 64;
constexpr int LOG2C  = 6;                     // A^64 = 6 squarings
constexpr int KCH    = T_LEN / CHUNK;         // 7500 chunks per row
constexpr int NT     = 128;                   // threads per block (2 waves)
constexpr int HISTC  = 12;                    // history chunks (768 samples)
constexpr int MTERM  = 12;                    // Horner terms (= horizon)
constexpr int OUTC   = NT - HISTC;            // 116 output chunks per block
constexpr int BLKROW = (KCH + OUTC - 1) / OUTC;  // 65 blocks per row
constexpr int NBLK   = B_ROWS * BLKROW;       // 4160 blocks
constexpr int NWAVE  = NT / 64;               // 2 waves

struct Coeffs { float b0, b1, b2, a1, a2; };

__device__ __forceinline__ float rfl(float v) {
    return __int_as_float(__builtin_amdgcn_readfirstlane(__float_as_int(v)));
}

__device__ __forceinline__ Coeffs shelf(float fc, float gdb, float Q) {
    float A  = powf(10.0f, gdb * (1.0f / 40.0f));
    float w0 = 2.0f * 3.14159265358979323846f * fc / 48000.0f;
    float sw = sinf(w0), cw = cosf(w0);
    float alpha = sw / (2.0f * Q);
    float sqA = sqrtf(A);
    float b0 = A * ((A + 1.0f) - (A - 1.0f) * cw + 2.0f * sqA * alpha);
    float b1 = 2.0f * A * ((A - 1.0f) - (A + 1.0f) * cw);
    float b2 = A * ((A + 1.0f) - (A - 1.0f) * cw - 2.0f * sqA * alpha);
    float a0 = (A + 1.0f) + (A - 1.0f) * cw + 2.0f * sqA * alpha;
    float a1 = -2.0f * ((A - 1.0f) + (A + 1.0f) * cw);
    float a2 = (A + 1.0f) + (A - 1.0f) * cw - 2.0f * sqA * alpha;
    float rr = 1.0f / a0;
    Coeffs c;
    c.b0 = rfl(b0 * rr); c.b1 = rfl(b1 * rr); c.b2 = rfl(b2 * rr);
    c.a1 = rfl(a1 * rr); c.a2 = rfl(a2 * rr);
    return c;
}

// DF2T biquad step, op-for-op as reference:
//   y = b0*x + z1; z1' = b1*x - a1*y + z2; z2' = b2*x - a2*y
__device__ __forceinline__ float bq(float xn, const Coeffs& c, float& z1, float& z2) {
    float y = fmaf(c.b0, xn, z1);
    z1 = fmaf(-c.a1, y, fmaf(c.b1, xn, z2));
    z2 = fmaf(c.b2, xn, -(c.a2 * y));
    return y;
}

__device__ __forceinline__ float step6(float s[6], float x,
                                       const Coeffs& c1, const Coeffs& c2, const Coeffs& c3) {
    float y1 = bq(x,  c1, s[0], s[1]);
    float y2 = bq(y1, c2, s[2], s[3]);
    float y3 = bq(y2, c3, s[4], s[5]);
    return y3;
}

// y0 + cn[n].t6 (cn rows stride-8; broadcast LDS reads, const offsets)
__device__ __forceinline__ float corr(float y0, const float* cnp, const float t6[6]) {
    float4 ca = *(const float4*)(cnp);
    float2 cb = *(const float2*)(cnp + 4);
    float acc = fmaf(ca.x, t6[0], y0);
    acc = fmaf(ca.y, t6[1], acc);
    acc = fmaf(ca.z, t6[2], acc);
    acc = fmaf(ca.w, t6[3], acc);
    acc = fmaf(cb.x, t6[4], acc);
    acc = fmaf(cb.y, t6[5], acc);
    return acc;
}

__global__ __launch_bounds__(128, 4) void k_fused(
    const float* __restrict__ x,
    const float* __restrict__ p_lg, const float* __restrict__ p_mg,
    const float* __restrict__ p_mf, const float* __restrict__ p_mq,
    const float* __restrict__ p_hg,
    float* __restrict__ out)
{
    // smem: [0..896) doubles as the per-thread d store (dl, stride 7);
    // after barrier2 the 8KB is two per-wave 4KB store-staging quarters.
    __shared__ __align__(16) float smem[2048];
    __shared__ float M[36];                      // A^64
    __shared__ float Pw[LOG2C * 36];             // A^1,A^2,A^4,A^8,A^16,A^32
    __shared__ float Crow[8];                    // output row C of the cascade
    __shared__ __align__(16) float cn[64 * 8];   // C*A^n rows, stride 8

    const int t    = threadIdx.x;
    const int lane = t & 63;
    const int w    = t >> 6;
    const int r = blockIdx.x / BLKROW;
    const int b = blockIdx.x - r * BLKROW;
    const int c = b * OUTC + t - HISTC;          // this thread's chunk index
    const int cbase = b * OUTC - HISTC;          // chunk index of thread 0
    const bool active = (c >= 0) && (c < KCH);

    Coeffs c1 = shelf(120.0f,  *p_lg, 0.707f);
    Coeffs c2 = shelf(*p_mf,   *p_mg, *p_mq);
    Coeffs c3 = shelf(4000.0f, *p_hg, 0.707f);

    // ---- load chunk into registers ----
    float4 xv[16];
    {
        int cc = c < 0 ? 0 : (c >= KCH ? KCH - 1 : c);
        const float4* lp = (const float4*)(x + (long long)r * T_LEN + (long long)cc * CHUNK);
        if (active) {
            #pragma unroll
            for (int q = 0; q < 16; ++q) xv[q] = lp[q];
        } else {
            #pragma unroll
            for (int q = 0; q < 16; ++q) xv[q] = make_float4(0.f, 0.f, 0.f, 0.f);
        }
    }

    // ---- wave 0: A columns + C row, then 6 shuffle-squarings, publish ----
    // Lane (i,j) = lane i*6+j holds A[i][j]; identical fma order to the
    // LDS version (acc=0; acc=fma(A[i][q],A[q][j],acc), q ascending).
    if (w == 0) {
        const int i  = lane / 6;                 // lanes >=36: clamped, unused
        const int j  = lane - 6 * i;
        const int i6 = i * 6;
        float e[6];
        #pragma unroll
        for (int jj = 0; jj < 6; ++jj) e[jj] = (jj == j) ? 1.0f : 0.0f;
        float y = step6(e, 0.0f, c1, c2, c3);    // e := A[:,j]; y = C[j]
        if (lane < 6) Crow[lane] = y;
        float aM = e[0];
        #pragma unroll
        for (int ii = 1; ii < 6; ++ii) aM = (i == ii) ? e[ii] : aM;
        for (int it = 0; it < LOG2C; ++it) {
            if (lane < 36) Pw[it * 36 + lane] = aM;   // snapshot A^(2^it)
            float acc = 0.f;
            #pragma unroll
            for (int q = 0; q < 6; ++q) {
                int sA = i6 + q; if (sA > 63) sA = 63;   // lanes >=36 only
                acc = fmaf(__shfl(aM, sA, 64), __shfl(aM, q * 6 + j, 64), acc);
            }
            aM = acc;
        }
        if (lane < 36) M[lane] = aM;             // A^64
    }

    // ---- pass 1: zero-state response, outputs written in place (y0) ----
    float s[6] = {0.f, 0.f, 0.f, 0.f, 0.f, 0.f};
    #pragma unroll
    for (int q = 0; q < 16; ++q) {
        float4 v = xv[q];
        v.x = step6(s, v.x, c1, c2, c3);
        v.y = step6(s, v.y, c1, c2, c3);
        v.z = step6(s, v.z, c1, c2, c3);
        v.w = step6(s, v.w, c1, c2, c3);
        xv[q] = v;
    }
    #pragma unroll
    for (int i = 0; i < 6; ++i) smem[t * 7 + i] = s[i];

    __syncthreads();                              // barrier1: dl + M + Pw + Crow

    float a[36];
    #pragma unroll
    for (int i = 0; i < 36; ++i) a[i] = rfl(M[i]);   // A^64 -> SGPRs

    // ---- cn rows on wave 1: cn[n] = C * prod_k A^(2^k * bit_k(n)) ----
    if (w == 1) {
        float row[6];
        #pragma unroll
        for (int jj = 0; jj < 6; ++jj) row[jj] = Crow[jj];
        #pragma unroll
        for (int k = 0; k < LOG2C; ++k) {
            if ((lane >> k) & 1) {
                const float* P = Pw + k * 36;
                float nr[6];
                #pragma unroll
                for (int jj = 0; jj < 6; ++jj) {
                    float acc = 0.f;
                    #pragma unroll
                    for (int q = 0; q < 6; ++q) acc = fmaf(row[q], P[q * 6 + jj], acc);
                    nr[jj] = acc;
                }
                #pragma unroll
                for (int jj = 0; jj < 6; ++jj) row[jj] = nr[jj];
            }
        }
        #pragma unroll
        for (int jj = 0; jj < 6; ++jj) cn[lane * 8 + jj] = row[jj];
    }

    // ---- truncated Horner scan over predecessors (oldest -> newest) ----
    float t6[6] = {0.f, 0.f, 0.f, 0.f, 0.f, 0.f};
    int m0 = t - MTERM; if (m0 < 0) m0 = 0;
    for (int m = m0; m < t; ++m) {
        float dm[6];
        #pragma unroll
        for (int i = 0; i < 6; ++i) dm[i] = smem[m * 7 + i];
        float nt6[6];
        #pragma unroll
        for (int i = 0; i < 6; ++i) {
            float acc = dm[i];
            #pragma unroll
            for (int j = 0; j < 6; ++j) acc = fmaf(a[i * 6 + j], t6[j], acc);
            nt6[i] = acc;
        }
        #pragma unroll
        for (int i = 0; i < 6; ++i) t6[i] = nt6[i];
    }

    __syncthreads();   // barrier2: cn ready; all dl reads done (smem reusable)

    // ---- combine: y[n] = y0[n] + cn[n].t6  (6 fma + 2 LDS bcast/sample) ----
    #pragma unroll
    for (int q = 0; q < 16; ++q) {
        float4 v = xv[q];
        v.x = corr(v.x, cn + (4 * q + 0) * 8, t6);
        v.y = corr(v.y, cn + (4 * q + 1) * 8, t6);
        v.z = corr(v.z, cn + (4 * q + 2) * 8, t6);
        v.w = corr(v.w, cn + (4 * q + 3) * 8, t6);
        xv[q] = v;
    }

    // ---- per-wave store staging, barrier-free (R5/R10 proven path) ----
    // Round j: source lanes 16j..16j+15 write their chunks (swizzled)
    // into this wave's quarter; all 64 lanes read back + store
    // 1KB-contiguous global. DS ops retire in-order per wave.
    float4* qv = ((float4*)smem) + w * 256;       // this wave's quarter
    float4* op = (float4*)(out + (long long)r * T_LEN);
    #pragma unroll
    for (int j = 0; j < 4; ++j) {
        if ((lane >> 4) == j) {
            const int sl  = lane & 15;
            const int key = sl & 7;
            #pragma unroll
            for (int q = 0; q < 16; ++q)
                qv[sl * 16 + (q ^ key)] = xv[q];
        }
        const long long base4 = (long long)(cbase + w * 64 + 16 * j) * 16;
        #pragma unroll
        for (int i = 0; i < 4; ++i) {
            const int sl = i * 4 + (lane >> 4);   // source slot in quarter
            const int qq = lane & 15;             // float4 within chunk
            const int tr = w * 64 + 16 * j + sl;  // owning thread index
            const int cc = cbase + tr;            // destination chunk
            if (tr >= HISTC && cc < KCH) {
                op[base4 + i * 64 + lane] = qv[sl * 16 + (qq ^ (sl & 7))];
            }
        }
    }
}

extern "C" void kernel_launch(void* const* d_in, const int* in_sizes, int n_in,
                              void* d_out, int out_size, void* d_ws, size_t ws_size,
                              hipStream_t stream) {
    const float* x  = (const float*)d_in[0];
    const float* lg = (const float*)d_in[1];
    const float* mg = (const float*)d_in[2];
    const float* mf = (const float*)d_in[3];
    const float* mq = (const float*)d_in[4];
    const float* hg = (const float*)d_in[5];
    float* out = (float*)d_out;

    hipLaunchKernelGGL(k_fused, dim3(NBLK), dim3(NT), 0, stream,
                       x, lg, mg, mf, mq, hg, out);
}